// Round 4
// baseline (365.680 us; speedup 1.0000x reference)
//
#include <hip/hip_runtime.h>
#include <hip/hip_bf16.h>

// Problem constants (fixed by reference setup_inputs)
#define B_ROWS 8192
#define D_DIM  768

// Main-kernel tile config: 128(I) x 256(J) block tile, K-step 32,
// 512 threads = 8 waves (2 wm x 4 wn), each wave owns a 64x64 output tile
// = 4x4 fragments of 16x16 per GEMM (3 GEMMs -> 48 f32x4 accumulators).
#define BI 128
#define BJ 256
#define BK 32
#define NTHREADS 512
#define KTILES (D_DIM / BK)            // 24
#define TILE_ELEMS (128 * BK)          // 4096 elems = 8192 B per panel-tile
#define PANEL_ELEMS ((size_t)B_ROWS * (size_t)D_DIM)   // 6291456
#define PANEL_BYTES (PANEL_ELEMS * 2)                  // 12582912 B

// LDS buffer layout (elems): sF@0(4096) sFM2@4096 sM2@8192 sBF@12288(8192) sBF2@20480(8192)
#define LDS_F    0
#define LDS_FM2  4096
#define LDS_M2   8192
#define LDS_BF   12288
#define LDS_BF2  20480
#define LDSBUF_ELEMS 28672             // 57344 B per buffer; x2 = 114688 B

typedef __attribute__((ext_vector_type(8))) short bf16x8;           // MFMA A/B frag (8 bf16)
typedef __attribute__((ext_vector_type(8))) unsigned short u16x8;   // 16B vector store
typedef __attribute__((ext_vector_type(4))) float f32x4;            // MFMA C/D frag

__device__ __forceinline__ unsigned short f2bf(float x) {
  unsigned int u = __float_as_uint(x);
  u += 0x7fffu + ((u >> 16) & 1u);
  return (unsigned short)(u >> 16);
}

__device__ __forceinline__ float4 f4mul(float4 a, float4 b) {
  return make_float4(a.x * b.x, a.y * b.y, a.z * b.z, a.w * b.w);
}

__device__ __forceinline__ u16x8 cvt8(float4 a, float4 b) {
  u16x8 v;
  v[0] = f2bf(a.x); v[1] = f2bf(a.y); v[2] = f2bf(a.z); v[3] = f2bf(a.w);
  v[4] = f2bf(b.x); v[5] = f2bf(b.y); v[6] = f2bf(b.z); v[7] = f2bf(b.w);
  return v;
}

// Direct global->LDS async copy, 16B per lane (wave-uniform LDS base + lane*16).
__device__ __forceinline__ void gload16(const void* g, void* l) {
  __builtin_amdgcn_global_load_lds(
      (const __attribute__((address_space(1))) unsigned int*)(uintptr_t)g,
      (__attribute__((address_space(3))) unsigned int*)(unsigned int)(uintptr_t)l,
      16, 0, 0);
}

// Pre-pass: fp32 inputs -> four bf16 operand panels, tiled panel[tr][tk][128][32]
// with XOR chunk-swizzle (chunk' = chunk ^ ((row>>1)&3), 8-elem chunks).
// FUSED: also accumulates rn[r] = sum_d f^2 m^2 via 32-lane reduce + atomicAdd
// (rn must be zeroed beforehand; 96 chunks/row = 3 aligned 32-lane groups).
__global__ __launch_bounds__(256) void convert_kernel(
    const float* __restrict__ f, const float* __restrict__ mask,
    unsigned short* __restrict__ pF, unsigned short* __restrict__ pFM2,
    unsigned short* __restrict__ pM2, unsigned short* __restrict__ pF2,
    float* __restrict__ rn) {
  const int g = blockIdx.x * 256 + threadIdx.x;   // 8192*96 chunks of 8 elems
  const int r = g / (D_DIM / 8);
  const int chunk = g - r * (D_DIM / 8);          // 0..95
  const float* fr = f + (size_t)r * D_DIM + chunk * 8;
  const float* mr = mask + (size_t)r * D_DIM + chunk * 8;
  float4 fv0 = *(const float4*)(fr);
  float4 fv1 = *(const float4*)(fr + 4);
  float4 mv0 = *(const float4*)(mr);
  float4 mv1 = *(const float4*)(mr + 4);
  float4 m20 = f4mul(mv0, mv0), m21 = f4mul(mv1, mv1);
  float4 fm0 = f4mul(fv0, m20), fm1 = f4mul(fv1, m21);
  float4 f20 = f4mul(fv0, fv0), f21 = f4mul(fv1, fv1);

  const int tr = r >> 7, rr = r & 127;
  const int tk = chunk >> 2, ch = chunk & 3;
  const int sc = (ch ^ ((rr >> 1) & 3)) << 3;     // swizzled elem col
  const size_t off = ((size_t)(tr * KTILES + tk)) * TILE_ELEMS + rr * 32 + sc;
  *(u16x8*)(pF + off)   = cvt8(fv0, fv1);
  *(u16x8*)(pFM2 + off) = cvt8(fm0, fm1);
  *(u16x8*)(pM2 + off)  = cvt8(m20, m21);
  *(u16x8*)(pF2 + off)  = cvt8(f20, f21);

  // row-norm^2 partial: sum f^2 m^2 over this thread's 8 elems
  float s = f20.x * m20.x + f20.y * m20.y + f20.z * m20.z + f20.w * m20.w
          + f21.x * m21.x + f21.y * m21.y + f21.z * m21.z + f21.w * m21.w;
  for (int o = 16; o > 0; o >>= 1) s += __shfl_down(s, o, 32);
  if ((threadIdx.x & 31) == 0) atomicAdd(&rn[r], s);
}

// Main kernel: fused triple-GEMM + loss. 128x256 tile, dbuf LDS, 4-phase
// K-step (T3+T4+T5): per phase {A-quadrant ds_read (+B in ph0), front-loaded
// prefetch gloads (ph0/ph1), barrier, setprio(1), 12 MFMA, setprio(0), barrier}.
// Single vmcnt(0) per K-step at phase 3 (loads issued >=2 phases earlier).
//  accS = f_i . f_j ; accN = (f_i*m2_i) . f_j ; accD = m2_i . f_j^2
__global__ __launch_bounds__(NTHREADS) void fused_loss_bf16_kernel(
    const unsigned short* __restrict__ pF, const unsigned short* __restrict__ pFM2,
    const unsigned short* __restrict__ pM2, const unsigned short* __restrict__ pF2,
    const float* __restrict__ rn, float* __restrict__ out) {
  __shared__ unsigned short lds[2 * LDSBUF_ELEMS];
  __shared__ float red[8];

  const int t    = threadIdx.x;
  const int lane = t & 63;
  const int wv   = t >> 6;        // wave id 0..7
  const int wm   = wv >> 2;       // 0..1  (row group of 64)
  const int wn   = wv & 3;        // 0..3  (col group of 64)
  const int frg  = lane & 15;     // fragment row
  const int ch   = lane >> 4;     // fragment k-chunk (8 bf16 = 16B)

  const int trA = blockIdx.y;     // i0 = trA*128
  const int trB = blockIdx.x;     // j0 = trB*256 -> panel row-tiles 2trB, 2trB+1
  const int te  = t * 8;          // staging elem offset (16B per thread)

  const size_t baseA  = (size_t)(trA * KTILES) * TILE_ELEMS;
  const size_t baseB0 = (size_t)((2 * trB) * KTILES) * TILE_ELEMS;
  const size_t baseB1 = (size_t)((2 * trB + 1) * KTILES) * TILE_ELEMS;

  // Precomputed swizzled ds_read elem offsets (fixed per thread).
  int offA[4], offB[4];
#pragma unroll
  for (int m = 0; m < 4; ++m) {
    const int rr = wm * 64 + m * 16 + frg;            // 0..127
    offA[m] = rr * 32 + ((ch ^ ((rr >> 1) & 3)) << 3);
  }
#pragma unroll
  for (int n = 0; n < 4; ++n) {
    const int rB = wn * 64 + n * 16 + frg;            // 0..255
    const int rt = rB >> 7, rr = rB & 127;
    offB[n] = rt * TILE_ELEMS + rr * 32 + ((ch ^ ((rr >> 1) & 3)) << 3);
  }

  f32x4 accS[4][4], accN[4][4], accD[4][4];
#pragma unroll
  for (int m = 0; m < 4; ++m)
#pragma unroll
    for (int n = 0; n < 4; ++n) {
      accS[m][n] = {0.f, 0.f, 0.f, 0.f};
      accN[m][n] = {0.f, 0.f, 0.f, 0.f};
      accD[m][n] = {0.f, 0.f, 0.f, 0.f};
    }

  unsigned short* const buf0 = lds;
  unsigned short* const buf1 = lds + LDSBUF_ELEMS;

  // Prologue: stage tile 0 fully, drain, sync.
  {
    const size_t tA  = baseA  + te;
    const size_t tB0 = baseB0 + te;
    const size_t tB1 = baseB1 + te;
    gload16(pF   + tA,  buf0 + LDS_F   + te);
    gload16(pFM2 + tA,  buf0 + LDS_FM2 + te);
    gload16(pM2  + tA,  buf0 + LDS_M2  + te);
    gload16(pF   + tB0, buf0 + LDS_BF  + te);
    gload16(pF   + tB1, buf0 + LDS_BF  + TILE_ELEMS + te);
    gload16(pF2  + tB0, buf0 + LDS_BF2 + te);
    gload16(pF2  + tB1, buf0 + LDS_BF2 + TILE_ELEMS + te);
  }
  asm volatile("s_waitcnt vmcnt(0)" ::: "memory");
  __syncthreads();

  int cur = 0;
  for (int tk = 0; tk < KTILES; ++tk) {
    unsigned short* const cb = cur ? buf1 : buf0;
    unsigned short* const nb = cur ? buf0 : buf1;
    const int pf = (tk + 1 < KTILES);
    const size_t tA  = baseA  + (size_t)(tk + 1) * TILE_ELEMS + te;
    const size_t tB0 = baseB0 + (size_t)(tk + 1) * TILE_ELEMS + te;
    const size_t tB1 = baseB1 + (size_t)(tk + 1) * TILE_ELEMS + te;

    // ---------------- phase 0: prefetch 4/7, read B + A[0], MFMA m=0 -------
    if (pf) {
      gload16(pF   + tA,  nb + LDS_F   + te);
      gload16(pFM2 + tA,  nb + LDS_FM2 + te);
      gload16(pM2  + tA,  nb + LDS_M2  + te);
      gload16(pF   + tB0, nb + LDS_BF  + te);
    }
    bf16x8 bF[4], bF2[4];
#pragma unroll
    for (int n = 0; n < 4; ++n) {
      bF[n]  = *(const bf16x8*)(cb + LDS_BF  + offB[n]);
      bF2[n] = *(const bf16x8*)(cb + LDS_BF2 + offB[n]);
    }
    {
      bf16x8 aF = *(const bf16x8*)(cb + LDS_F   + offA[0]);
      bf16x8 aN = *(const bf16x8*)(cb + LDS_FM2 + offA[0]);
      bf16x8 aD = *(const bf16x8*)(cb + LDS_M2  + offA[0]);
      __builtin_amdgcn_s_barrier();
      __builtin_amdgcn_s_setprio(1);
#pragma unroll
      for (int n = 0; n < 4; ++n) {
        accS[0][n] = __builtin_amdgcn_mfma_f32_16x16x32_bf16(aF, bF[n],  accS[0][n], 0, 0, 0);
        accN[0][n] = __builtin_amdgcn_mfma_f32_16x16x32_bf16(aN, bF[n],  accN[0][n], 0, 0, 0);
        accD[0][n] = __builtin_amdgcn_mfma_f32_16x16x32_bf16(aD, bF2[n], accD[0][n], 0, 0, 0);
      }
      __builtin_amdgcn_s_setprio(0);
      __builtin_amdgcn_s_barrier();
    }
    // ---------------- phase 1: prefetch 3/7, read A[1], MFMA m=1 -----------
    if (pf) {
      gload16(pF   + tB1, nb + LDS_BF  + TILE_ELEMS + te);
      gload16(pF2  + tB0, nb + LDS_BF2 + te);
      gload16(pF2  + tB1, nb + LDS_BF2 + TILE_ELEMS + te);
    }
    {
      bf16x8 aF = *(const bf16x8*)(cb + LDS_F   + offA[1]);
      bf16x8 aN = *(const bf16x8*)(cb + LDS_FM2 + offA[1]);
      bf16x8 aD = *(const bf16x8*)(cb + LDS_M2  + offA[1]);
      __builtin_amdgcn_s_barrier();
      __builtin_amdgcn_s_setprio(1);
#pragma unroll
      for (int n = 0; n < 4; ++n) {
        accS[1][n] = __builtin_amdgcn_mfma_f32_16x16x32_bf16(aF, bF[n],  accS[1][n], 0, 0, 0);
        accN[1][n] = __builtin_amdgcn_mfma_f32_16x16x32_bf16(aN, bF[n],  accN[1][n], 0, 0, 0);
        accD[1][n] = __builtin_amdgcn_mfma_f32_16x16x32_bf16(aD, bF2[n], accD[1][n], 0, 0, 0);
      }
      __builtin_amdgcn_s_setprio(0);
      __builtin_amdgcn_s_barrier();
    }
    // ---------------- phase 2: read A[2], MFMA m=2 -------------------------
    {
      bf16x8 aF = *(const bf16x8*)(cb + LDS_F   + offA[2]);
      bf16x8 aN = *(const bf16x8*)(cb + LDS_FM2 + offA[2]);
      bf16x8 aD = *(const bf16x8*)(cb + LDS_M2  + offA[2]);
      __builtin_amdgcn_s_barrier();
      __builtin_amdgcn_s_setprio(1);
#pragma unroll
      for (int n = 0; n < 4; ++n) {
        accS[2][n] = __builtin_amdgcn_mfma_f32_16x16x32_bf16(aF, bF[n],  accS[2][n], 0, 0, 0);
        accN[2][n] = __builtin_amdgcn_mfma_f32_16x16x32_bf16(aN, bF[n],  accN[2][n], 0, 0, 0);
        accD[2][n] = __builtin_amdgcn_mfma_f32_16x16x32_bf16(aD, bF2[n], accD[2][n], 0, 0, 0);
      }
      __builtin_amdgcn_s_setprio(0);
      __builtin_amdgcn_s_barrier();
    }
    // ---------------- phase 3: read A[3], MFMA m=3, drain, swap ------------
    {
      bf16x8 aF = *(const bf16x8*)(cb + LDS_F   + offA[3]);
      bf16x8 aN = *(const bf16x8*)(cb + LDS_FM2 + offA[3]);
      bf16x8 aD = *(const bf16x8*)(cb + LDS_M2  + offA[3]);
      __builtin_amdgcn_s_barrier();
      __builtin_amdgcn_s_setprio(1);
#pragma unroll
      for (int n = 0; n < 4; ++n) {
        accS[3][n] = __builtin_amdgcn_mfma_f32_16x16x32_bf16(aF, bF[n],  accS[3][n], 0, 0, 0);
        accN[3][n] = __builtin_amdgcn_mfma_f32_16x16x32_bf16(aN, bF[n],  accN[3][n], 0, 0, 0);
        accD[3][n] = __builtin_amdgcn_mfma_f32_16x16x32_bf16(aD, bF2[n], accD[3][n], 0, 0, 0);
      }
      __builtin_amdgcn_s_setprio(0);
      // All 7 prefetch gloads were issued >=2 phases ago -> near-free drain.
      asm volatile("s_waitcnt vmcnt(0)" ::: "memory");
      __builtin_amdgcn_s_barrier();
    }
    cur ^= 1;
  }

  // ---- epilogue: pointwise loss + off-diagonal masked reduction ----
  // C/D layout (m89-verified): col = lane&15, row = (lane>>4)*4 + reg
  float sum = 0.f;
  const int r4 = (lane >> 4) * 4;
  const int cc = lane & 15;
  const int i0 = trA * BI;
  const int j0 = trB * BJ;
#pragma unroll
  for (int m = 0; m < 4; ++m) {
    const int gi_base = i0 + wm * 64 + m * 16 + r4;
#pragma unroll
    for (int jj = 0; jj < 4; ++jj) {
      const int gi = gi_base + jj;
      // rn holds sum_d f^2 m^2 ; 1/max(sqrt(s),1e-12) == rsqrt(max(s,1e-24))
      const float rni = rsqrtf(fmaxf(rn[gi], 1e-24f));
#pragma unroll
      for (int n = 0; n < 4; ++n) {
        const int gj = j0 + wn * 64 + n * 16 + cc;
        const float sfull = accS[m][n][jj];
        const float num   = accN[m][n][jj];
        const float nd    = accD[m][n][jj];
        const float rnij  = rsqrtf(fmaxf(nd, 1e-24f));
        const float sim   = num * rni * rnij;
        const float d     = fabsf(sfull - sim);
        if (gi != gj) sum += d;
      }
    }
  }
  for (int off = 32; off > 0; off >>= 1) sum += __shfl_down(sum, off);
  if (lane == 0) red[wv] = sum;
  __syncthreads();
  if (t == 0) {
    float bs = 0.f;
    for (int w = 0; w < 8; ++w) bs += red[w];
    const float scale = 1.0f / (8192.0f * 8191.0f);
    atomicAdd(out, bs * scale);
  }
}

// ---------------- Fallback path (ws too small): round-1 kernels ---------------
__global__ __launch_bounds__(256) void rownorm_zero_kernel(
    const float* __restrict__ f, const float* __restrict__ mask,
    float* __restrict__ rn_i, float* __restrict__ out) {
  if (blockIdx.x == 0 && threadIdx.x == 0) out[0] = 0.0f;
  const int wv = threadIdx.x >> 6;
  const int lane = threadIdx.x & 63;
  const int row = blockIdx.x * 4 + wv;
  const float* fr = f + (size_t)row * D_DIM;
  const float* mr = mask + (size_t)row * D_DIM;
  float s = 0.f;
  for (int d = lane; d < D_DIM; d += 64) {
    float v = fr[d] * mr[d];
    s += v * v;
  }
  for (int off = 32; off > 0; off >>= 1) s += __shfl_down(s, off);
  if (lane == 0) rn_i[row] = 1.0f / fmaxf(sqrtf(s), 1e-12f);
}

__global__ __launch_bounds__(NTHREADS, 2) void fused_loss_kernel(
    const float* __restrict__ f, const float* __restrict__ mask,
    const float* __restrict__ rn_i, float* __restrict__ out) {
  __shared__ unsigned short sF[128][BK];
  __shared__ unsigned short sFM2[128][BK];
  __shared__ unsigned short sM2[128][BK];
  __shared__ unsigned short sBF[128][BK];
  __shared__ unsigned short sBF2[128][BK];
  __shared__ float red[8];

  const int t    = threadIdx.x;
  const int lane = t & 63;
  const int wv   = t >> 6;
  const int wm   = wv >> 2;
  const int wn   = wv & 3;
  const int frg  = lane & 15;
  const int ko   = (lane >> 4) * 8;

  const int i0 = blockIdx.y * 128;
  const int j0 = blockIdx.x * 128;
  const int ar = t >> 2;
  const int ac = (t & 3) * 8;

  f32x4 accS[4][2], accN[4][2], accD[4][2];
  for (int m = 0; m < 4; ++m)
    for (int n = 0; n < 2; ++n) {
      accS[m][n] = {0.f, 0.f, 0.f, 0.f};
      accN[m][n] = {0.f, 0.f, 0.f, 0.f};
      accD[m][n] = {0.f, 0.f, 0.f, 0.f};
    }

  const float* fA = f    + (size_t)(i0 + ar) * D_DIM + ac;
  const float* mA = mask + (size_t)(i0 + ar) * D_DIM + ac;
  const float* fB = f    + (size_t)(j0 + ar) * D_DIM + ac;

  for (int k0 = 0; k0 < D_DIM; k0 += BK) {
    __syncthreads();
    float4 fa0 = *(const float4*)(fA + k0);
    float4 fa1 = *(const float4*)(fA + k0 + 4);
    float4 ma0 = *(const float4*)(mA + k0);
    float4 ma1 = *(const float4*)(mA + k0 + 4);
    float4 fb0 = *(const float4*)(fB + k0);
    float4 fb1 = *(const float4*)(fB + k0 + 4);
    float4 m20 = f4mul(ma0, ma0), m21 = f4mul(ma1, ma1);
    float4 fm0 = f4mul(fa0, m20), fm1 = f4mul(fa1, m21);
    float4 f20 = f4mul(fb0, fb0), f21 = f4mul(fb1, fb1);
    *(u16x8*)&sF[ar][ac]   = cvt8(fa0, fa1);
    *(u16x8*)&sFM2[ar][ac] = cvt8(fm0, fm1);
    *(u16x8*)&sM2[ar][ac]  = cvt8(m20, m21);
    *(u16x8*)&sBF[ar][ac]  = cvt8(fb0, fb1);
    *(u16x8*)&sBF2[ar][ac] = cvt8(f20, f21);
    __syncthreads();
    bf16x8 bF[2], bF2[2];
    for (int n = 0; n < 2; ++n) {
      bF[n]  = *(const bf16x8*)&sBF [wn * 32 + n * 16 + frg][ko];
      bF2[n] = *(const bf16x8*)&sBF2[wn * 32 + n * 16 + frg][ko];
    }
#pragma unroll
    for (int m = 0; m < 4; ++m) {
      bf16x8 aF = *(const bf16x8*)&sF  [wm * 64 + m * 16 + frg][ko];
      bf16x8 aN = *(const bf16x8*)&sFM2[wm * 64 + m * 16 + frg][ko];
      bf16x8 aD = *(const bf16x8*)&sM2 [wm * 64 + m * 16 + frg][ko];
#pragma unroll
      for (int n = 0; n < 2; ++n) {
        accS[m][n] = __builtin_amdgcn_mfma_f32_16x16x32_bf16(aF, bF[n],  accS[m][n], 0, 0, 0);
        accN[m][n] = __builtin_amdgcn_mfma_f32_16x16x32_bf16(aN, bF[n],  accN[m][n], 0, 0, 0);
        accD[m][n] = __builtin_amdgcn_mfma_f32_16x16x32_bf16(aD, bF2[n], accD[m][n], 0, 0, 0);
      }
    }
  }

  float sum = 0.f;
  const int r4 = (lane >> 4) * 4;
  const int cc = lane & 15;
#pragma unroll
  for (int m = 0; m < 4; ++m) {
    const int gi_base = i0 + wm * 64 + m * 16 + r4;
#pragma unroll
    for (int jj = 0; jj < 4; ++jj) {
      const int gi = gi_base + jj;
      const float rni = rn_i[gi];
#pragma unroll
      for (int n = 0; n < 2; ++n) {
        const int gj = j0 + wn * 32 + n * 16 + cc;
        const float sfull = accS[m][n][jj];
        const float num   = accN[m][n][jj];
        const float nd    = accD[m][n][jj];
        const float rnij  = rsqrtf(fmaxf(nd, 1e-24f));
        const float sim   = num * rni * rnij;
        const float d     = fabsf(sfull - sim);
        if (gi != gj) sum += d;
      }
    }
  }
  for (int off = 32; off > 0; off >>= 1) sum += __shfl_down(sum, off);
  if (lane == 0) red[wv] = sum;
  __syncthreads();
  if (t == 0) {
    float bs = 0.f;
    for (int w = 0; w < 8; ++w) bs += red[w];
    const float scale = 1.0f / (8192.0f * 8191.0f);
    atomicAdd(out, bs * scale);
  }
}

extern "C" void kernel_launch(void* const* d_in, const int* in_sizes, int n_in,
                              void* d_out, int out_size, void* d_ws, size_t ws_size,
                              hipStream_t stream) {
  const float* f    = (const float*)d_in[0];   // full_emb [8192,768] fp32
  const float* mask = (const float*)d_in[1];   // query_mask [8192,768] fp32
  float* out = (float*)d_out;                  // scalar loss

  const size_t need = 4 * PANEL_BYTES + (size_t)B_ROWS * sizeof(float);
  if (ws_size >= need) {
    unsigned short* pF   = (unsigned short*)d_ws;
    unsigned short* pFM2 = pF + PANEL_ELEMS;
    unsigned short* pM2  = pFM2 + PANEL_ELEMS;
    unsigned short* pF2  = pM2 + PANEL_ELEMS;
    float* rn = (float*)(pF2 + PANEL_ELEMS);
    hipMemsetAsync(rn, 0, B_ROWS * sizeof(float), stream);
    hipMemsetAsync(out, 0, sizeof(float), stream);
    convert_kernel<<<(B_ROWS * (D_DIM / 8)) / 256, 256, 0, stream>>>(
        f, mask, pF, pFM2, pM2, pF2, rn);
    dim3 grid(B_ROWS / BJ, B_ROWS / BI);   // 32 x 64
    fused_loss_bf16_kernel<<<grid, NTHREADS, 0, stream>>>(pF, pFM2, pM2, pF2, rn, out);
  } else {
    float* rn_i = (float*)d_ws;
    rownorm_zero_kernel<<<B_ROWS / 4, 256, 0, stream>>>(f, mask, rn_i, out);
    dim3 grid(B_ROWS / 128, B_ROWS / 128);
    fused_loss_kernel<<<grid, NTHREADS, 0, stream>>>(f, mask, rn_i, out);
  }
}

// Round 5
// 363.930 us; speedup vs baseline: 1.0048x; 1.0048x over previous
//
#include <hip/hip_runtime.h>
#include <hip/hip_bf16.h>

// Problem constants (fixed by reference setup_inputs)
#define B_ROWS 8192
#define D_DIM  768

// Main-kernel tile config: 128(I) x 256(J) block tile, K-step 32,
// 512 threads = 8 waves (2 wm x 4 wn), each wave owns a 64x64 output tile
// = 2x2 tiles of 32x32 per GEMM (3 GEMMs -> 12 f32x16 accumulators).
#define BI 128
#define BJ 256
#define BK 32
#define NTHREADS 512
#define KTILES (D_DIM / BK)            // 24
#define TILE_ELEMS (128 * BK)          // 4096 elems = 8192 B per panel-tile
#define PANEL_ELEMS ((size_t)B_ROWS * (size_t)D_DIM)   // 6291456
#define PANEL_BYTES (PANEL_ELEMS * 2)                  // 12582912 B

// LDS buffer layout (elems): sF@0(4096) sFM2@4096 sM2@8192 sBF@12288(8192) sBF2@20480(8192)
#define LDS_F    0
#define LDS_FM2  4096
#define LDS_M2   8192
#define LDS_BF   12288
#define LDS_BF2  20480
#define LDSBUF_ELEMS 28672             // 57344 B per buffer; x2 = 114688 B

typedef __attribute__((ext_vector_type(8))) short bf16x8;           // MFMA A/B frag (8 bf16)
typedef __attribute__((ext_vector_type(8))) unsigned short u16x8;   // 16B vector store
typedef __attribute__((ext_vector_type(4))) float f32x4;            // 16x16 C/D frag (fallback)
typedef __attribute__((ext_vector_type(16))) float f32x16;          // 32x32 C/D frag

__device__ __forceinline__ unsigned short f2bf(float x) {
  unsigned int u = __float_as_uint(x);
  u += 0x7fffu + ((u >> 16) & 1u);
  return (unsigned short)(u >> 16);
}

__device__ __forceinline__ float4 f4mul(float4 a, float4 b) {
  return make_float4(a.x * b.x, a.y * b.y, a.z * b.z, a.w * b.w);
}

__device__ __forceinline__ u16x8 cvt8(float4 a, float4 b) {
  u16x8 v;
  v[0] = f2bf(a.x); v[1] = f2bf(a.y); v[2] = f2bf(a.z); v[3] = f2bf(a.w);
  v[4] = f2bf(b.x); v[5] = f2bf(b.y); v[6] = f2bf(b.z); v[7] = f2bf(b.w);
  return v;
}

// Direct global->LDS async copy, 16B per lane (wave-uniform LDS base + lane*16).
__device__ __forceinline__ void gload16(const void* g, void* l) {
  __builtin_amdgcn_global_load_lds(
      (const __attribute__((address_space(1))) unsigned int*)(uintptr_t)g,
      (__attribute__((address_space(3))) unsigned int*)(unsigned int)(uintptr_t)l,
      16, 0, 0);
}

// Pre-pass: fp32 inputs -> four bf16 operand panels, tiled panel[tr][tk][128][32]
// with XOR chunk-swizzle (chunk' = chunk ^ ((row>>1)&3), 8-elem chunks).
// FUSED: also accumulates rn[r] = sum_d f^2 m^2 via 32-lane reduce + atomicAdd
// (rn must be zeroed beforehand; 96 chunks/row = 3 aligned 32-lane groups).
__global__ __launch_bounds__(256) void convert_kernel(
    const float* __restrict__ f, const float* __restrict__ mask,
    unsigned short* __restrict__ pF, unsigned short* __restrict__ pFM2,
    unsigned short* __restrict__ pM2, unsigned short* __restrict__ pF2,
    float* __restrict__ rn) {
  const int g = blockIdx.x * 256 + threadIdx.x;   // 8192*96 chunks of 8 elems
  const int r = g / (D_DIM / 8);
  const int chunk = g - r * (D_DIM / 8);          // 0..95
  const float* fr = f + (size_t)r * D_DIM + chunk * 8;
  const float* mr = mask + (size_t)r * D_DIM + chunk * 8;
  float4 fv0 = *(const float4*)(fr);
  float4 fv1 = *(const float4*)(fr + 4);
  float4 mv0 = *(const float4*)(mr);
  float4 mv1 = *(const float4*)(mr + 4);
  float4 m20 = f4mul(mv0, mv0), m21 = f4mul(mv1, mv1);
  float4 fm0 = f4mul(fv0, m20), fm1 = f4mul(fv1, m21);
  float4 f20 = f4mul(fv0, fv0), f21 = f4mul(fv1, fv1);

  const int tr = r >> 7, rr = r & 127;
  const int tk = chunk >> 2, ch = chunk & 3;
  const int sc = (ch ^ ((rr >> 1) & 3)) << 3;     // swizzled elem col
  const size_t off = ((size_t)(tr * KTILES + tk)) * TILE_ELEMS + rr * 32 + sc;
  *(u16x8*)(pF + off)   = cvt8(fv0, fv1);
  *(u16x8*)(pFM2 + off) = cvt8(fm0, fm1);
  *(u16x8*)(pM2 + off)  = cvt8(m20, m21);
  *(u16x8*)(pF2 + off)  = cvt8(f20, f21);

  // row-norm^2 partial: sum f^2 m^2 over this thread's 8 elems
  float s = f20.x * m20.x + f20.y * m20.y + f20.z * m20.z + f20.w * m20.w
          + f21.x * m21.x + f21.y * m21.y + f21.z * m21.z + f21.w * m21.w;
  for (int o = 16; o > 0; o >>= 1) s += __shfl_down(s, o, 32);
  if ((threadIdx.x & 31) == 0) atomicAdd(&rn[r], s);
}

// Main kernel: fused triple-GEMM + loss. 128x256 tile, dbuf LDS, R3-proven
// 2-barrier loop (prefetch issued before compute, single vmcnt(0)+barrier
// after), 32x32x16 MFMA (1.2x pipe rate vs 16x16x32, same LDS traffic).
//  accS = f_i . f_j ; accN = (f_i*m2_i) . f_j ; accD = m2_i . f_j^2
__global__ __launch_bounds__(NTHREADS) void fused_loss_bf16_kernel(
    const unsigned short* __restrict__ pF, const unsigned short* __restrict__ pFM2,
    const unsigned short* __restrict__ pM2, const unsigned short* __restrict__ pF2,
    const float* __restrict__ rn, float* __restrict__ out) {
  __shared__ unsigned short lds[2 * LDSBUF_ELEMS];
  __shared__ float red[8];

  const int t    = threadIdx.x;
  const int lane = t & 63;
  const int wv   = t >> 6;        // wave id 0..7
  const int wm   = wv >> 2;       // 0..1  (row group of 64)
  const int wn   = wv & 3;        // 0..3  (col group of 64)
  const int rl   = lane & 31;     // fragment row within 32-row block
  const int u    = lane >> 5;     // k-subchunk selector (0/1)

  const int trA = blockIdx.y;     // i0 = trA*128
  const int trB = blockIdx.x;     // j0 = trB*256 -> panel row-tiles 2trB, 2trB+1
  const int te  = t * 8;          // staging elem offset (16B per thread)

  const size_t baseA  = (size_t)(trA * KTILES) * TILE_ELEMS;
  const size_t baseB0 = (size_t)((2 * trB) * KTILES) * TILE_ELEMS;
  const size_t baseB1 = (size_t)((2 * trB + 1) * KTILES) * TILE_ELEMS;

  // Precomputed swizzled ds_read elem offsets (fixed per thread).
  // 32x32x16 A/B frag: row = base + (lane&31), 8 contiguous k at
  // k-chunk (2h + lane>>5); LDS chunk-swizzle ^((row>>1)&3) applied.
  int offA[2][2], offB[2][2];
#pragma unroll
  for (int mt = 0; mt < 2; ++mt)
#pragma unroll
    for (int h = 0; h < 2; ++h) {
      const int r = wm * 64 + mt * 32 + rl;             // 0..127
      offA[mt][h] = r * 32 + (((2 * h + u) ^ ((r >> 1) & 3)) << 3);
    }
#pragma unroll
  for (int nt = 0; nt < 2; ++nt)
#pragma unroll
    for (int h = 0; h < 2; ++h) {
      const int rB = wn * 64 + nt * 32 + rl;            // 0..255
      const int rt = rB >> 7, rr = rB & 127;
      offB[nt][h] = rt * TILE_ELEMS + rr * 32 + (((2 * h + u) ^ ((rr >> 1) & 3)) << 3);
    }

  f32x16 accS[2][2], accN[2][2], accD[2][2];
#pragma unroll
  for (int mt = 0; mt < 2; ++mt)
#pragma unroll
    for (int nt = 0; nt < 2; ++nt) {
#pragma unroll
      for (int r = 0; r < 16; ++r) {
        accS[mt][nt][r] = 0.f;
        accN[mt][nt][r] = 0.f;
        accD[mt][nt][r] = 0.f;
      }
    }

#define STAGE(b, tk)                                                          \
  do {                                                                        \
    const size_t _tA  = baseA  + (size_t)(tk) * TILE_ELEMS + te;              \
    const size_t _tB0 = baseB0 + (size_t)(tk) * TILE_ELEMS + te;              \
    const size_t _tB1 = baseB1 + (size_t)(tk) * TILE_ELEMS + te;              \
    gload16(pF   + _tA,  (b) + LDS_F   + te);                                 \
    gload16(pFM2 + _tA,  (b) + LDS_FM2 + te);                                 \
    gload16(pM2  + _tA,  (b) + LDS_M2  + te);                                 \
    gload16(pF   + _tB0, (b) + LDS_BF  + te);                                 \
    gload16(pF   + _tB1, (b) + LDS_BF  + TILE_ELEMS + te);                    \
    gload16(pF2  + _tB0, (b) + LDS_BF2 + te);                                 \
    gload16(pF2  + _tB1, (b) + LDS_BF2 + TILE_ELEMS + te);                    \
  } while (0)

  unsigned short* const buf0 = lds;
  unsigned short* const buf1 = lds + LDSBUF_ELEMS;

  STAGE(buf0, 0);
  asm volatile("s_waitcnt vmcnt(0)" ::: "memory");
  __syncthreads();

  int cur = 0;
  for (int tk = 0; tk < KTILES; ++tk) {
    unsigned short* const cb = cur ? buf1 : buf0;
    unsigned short* const nb = cur ? buf0 : buf1;
    if (tk + 1 < KTILES) STAGE(nb, tk + 1);   // prefetch issued BEFORE compute

    bf16x8 bF[2][2], bF2[2][2];               // [nt][h] : 8 frags = 32 VGPR
#pragma unroll
    for (int nt = 0; nt < 2; ++nt)
#pragma unroll
      for (int h = 0; h < 2; ++h) {
        bF[nt][h]  = *(const bf16x8*)(cb + LDS_BF  + offB[nt][h]);
        bF2[nt][h] = *(const bf16x8*)(cb + LDS_BF2 + offB[nt][h]);
      }
#pragma unroll
    for (int mt = 0; mt < 2; ++mt) {
#pragma unroll
      for (int h = 0; h < 2; ++h) {
        bf16x8 aF = *(const bf16x8*)(cb + LDS_F   + offA[mt][h]);
        bf16x8 aN = *(const bf16x8*)(cb + LDS_FM2 + offA[mt][h]);
        bf16x8 aD = *(const bf16x8*)(cb + LDS_M2  + offA[mt][h]);
#pragma unroll
        for (int nt = 0; nt < 2; ++nt) {
          accS[mt][nt] = __builtin_amdgcn_mfma_f32_32x32x16_bf16(aF, bF[nt][h],  accS[mt][nt], 0, 0, 0);
          accN[mt][nt] = __builtin_amdgcn_mfma_f32_32x32x16_bf16(aN, bF[nt][h],  accN[mt][nt], 0, 0, 0);
          accD[mt][nt] = __builtin_amdgcn_mfma_f32_32x32x16_bf16(aD, bF2[nt][h], accD[mt][nt], 0, 0, 0);
        }
      }
    }
    // Drain prefetch (issued one full compute-phase ago) then swap buffers.
    asm volatile("s_waitcnt vmcnt(0)" ::: "memory");
    __syncthreads();
    cur ^= 1;
  }
#undef STAGE

  // ---- epilogue: pointwise loss + off-diagonal masked reduction ----
  // 32x32 C/D layout (m74/m101-verified): col = lane&31,
  // row = (reg&3) + 8*(reg>>2) + 4*(lane>>5)
  float sum = 0.f;
  const int i0 = trA * BI;
  const int j0 = trB * BJ;
  const int rhi = u * 4;
#pragma unroll
  for (int mt = 0; mt < 2; ++mt) {
#pragma unroll
    for (int r = 0; r < 16; ++r) {
      const int row = (r & 3) + 8 * (r >> 2) + rhi;
      const int gi = i0 + wm * 64 + mt * 32 + row;
      // rn holds sum_d f^2 m^2 ; 1/max(sqrt(s),1e-12) == rsqrt(max(s,1e-24))
      const float rni = rsqrtf(fmaxf(rn[gi], 1e-24f));
#pragma unroll
      for (int nt = 0; nt < 2; ++nt) {
        const int gj = j0 + wn * 64 + nt * 32 + rl;
        const float sfull = accS[mt][nt][r];
        const float num   = accN[mt][nt][r];
        const float nd    = accD[mt][nt][r];
        const float rnij  = rsqrtf(fmaxf(nd, 1e-24f));
        const float sim   = num * rni * rnij;
        const float d     = fabsf(sfull - sim);
        if (gi != gj) sum += d;
      }
    }
  }
  for (int off = 32; off > 0; off >>= 1) sum += __shfl_down(sum, off);
  if (lane == 0) red[wv] = sum;
  __syncthreads();
  if (t == 0) {
    float bs = 0.f;
    for (int w = 0; w < 8; ++w) bs += red[w];
    const float scale = 1.0f / (8192.0f * 8191.0f);
    atomicAdd(out, bs * scale);
  }
}

// ---------------- Fallback path (ws too small): round-1 kernels ---------------
__global__ __launch_bounds__(256) void rownorm_zero_kernel(
    const float* __restrict__ f, const float* __restrict__ mask,
    float* __restrict__ rn_i, float* __restrict__ out) {
  if (blockIdx.x == 0 && threadIdx.x == 0) out[0] = 0.0f;
  const int wv = threadIdx.x >> 6;
  const int lane = threadIdx.x & 63;
  const int row = blockIdx.x * 4 + wv;
  const float* fr = f + (size_t)row * D_DIM;
  const float* mr = mask + (size_t)row * D_DIM;
  float s = 0.f;
  for (int d = lane; d < D_DIM; d += 64) {
    float v = fr[d] * mr[d];
    s += v * v;
  }
  for (int off = 32; off > 0; off >>= 1) s += __shfl_down(s, off);
  if (lane == 0) rn_i[row] = 1.0f / fmaxf(sqrtf(s), 1e-12f);
}

__global__ __launch_bounds__(NTHREADS, 2) void fused_loss_kernel(
    const float* __restrict__ f, const float* __restrict__ mask,
    const float* __restrict__ rn_i, float* __restrict__ out) {
  __shared__ unsigned short sF[128][BK];
  __shared__ unsigned short sFM2[128][BK];
  __shared__ unsigned short sM2[128][BK];
  __shared__ unsigned short sBF[128][BK];
  __shared__ unsigned short sBF2[128][BK];
  __shared__ float red[8];

  const int t    = threadIdx.x;
  const int lane = t & 63;
  const int wv   = t >> 6;
  const int wm   = wv >> 2;
  const int wn   = wv & 3;
  const int frg  = lane & 15;
  const int ko   = (lane >> 4) * 8;

  const int i0 = blockIdx.y * 128;
  const int j0 = blockIdx.x * 128;
  const int ar = t >> 2;
  const int ac = (t & 3) * 8;

  f32x4 accS[4][2], accN[4][2], accD[4][2];
  for (int m = 0; m < 4; ++m)
    for (int n = 0; n < 2; ++n) {
      accS[m][n] = {0.f, 0.f, 0.f, 0.f};
      accN[m][n] = {0.f, 0.f, 0.f, 0.f};
      accD[m][n] = {0.f, 0.f, 0.f, 0.f};
    }

  const float* fA = f    + (size_t)(i0 + ar) * D_DIM + ac;
  const float* mA = mask + (size_t)(i0 + ar) * D_DIM + ac;
  const float* fB = f    + (size_t)(j0 + ar) * D_DIM + ac;

  for (int k0 = 0; k0 < D_DIM; k0 += BK) {
    __syncthreads();
    float4 fa0 = *(const float4*)(fA + k0);
    float4 fa1 = *(const float4*)(fA + k0 + 4);
    float4 ma0 = *(const float4*)(mA + k0);
    float4 ma1 = *(const float4*)(mA + k0 + 4);
    float4 fb0 = *(const float4*)(fB + k0);
    float4 fb1 = *(const float4*)(fB + k0 + 4);
    float4 m20 = f4mul(ma0, ma0), m21 = f4mul(ma1, ma1);
    float4 fm0 = f4mul(fa0, m20), fm1 = f4mul(fa1, m21);
    float4 f20 = f4mul(fb0, fb0), f21 = f4mul(fb1, fb1);
    *(u16x8*)&sF[ar][ac]   = cvt8(fa0, fa1);
    *(u16x8*)&sFM2[ar][ac] = cvt8(fm0, fm1);
    *(u16x8*)&sM2[ar][ac]  = cvt8(m20, m21);
    *(u16x8*)&sBF[ar][ac]  = cvt8(fb0, fb1);
    *(u16x8*)&sBF2[ar][ac] = cvt8(f20, f21);
    __syncthreads();
    bf16x8 bF[2], bF2[2];
    for (int n = 0; n < 2; ++n) {
      bF[n]  = *(const bf16x8*)&sBF [wn * 32 + n * 16 + frg][ko];
      bF2[n] = *(const bf16x8*)&sBF2[wn * 32 + n * 16 + frg][ko];
    }
#pragma unroll
    for (int m = 0; m < 4; ++m) {
      bf16x8 aF = *(const bf16x8*)&sF  [wm * 64 + m * 16 + frg][ko];
      bf16x8 aN = *(const bf16x8*)&sFM2[wm * 64 + m * 16 + frg][ko];
      bf16x8 aD = *(const bf16x8*)&sM2 [wm * 64 + m * 16 + frg][ko];
#pragma unroll
      for (int n = 0; n < 2; ++n) {
        accS[m][n] = __builtin_amdgcn_mfma_f32_16x16x32_bf16(aF, bF[n],  accS[m][n], 0, 0, 0);
        accN[m][n] = __builtin_amdgcn_mfma_f32_16x16x32_bf16(aN, bF[n],  accN[m][n], 0, 0, 0);
        accD[m][n] = __builtin_amdgcn_mfma_f32_16x16x32_bf16(aD, bF2[n], accD[m][n], 0, 0, 0);
      }
    }
  }

  float sum = 0.f;
  const int r4 = (lane >> 4) * 4;
  const int cc = lane & 15;
#pragma unroll
  for (int m = 0; m < 4; ++m) {
    const int gi_base = i0 + wm * 64 + m * 16 + r4;
#pragma unroll
    for (int jj = 0; jj < 4; ++jj) {
      const int gi = gi_base + jj;
      const float rni = rn_i[gi];
#pragma unroll
      for (int n = 0; n < 2; ++n) {
        const int gj = j0 + wn * 32 + n * 16 + cc;
        const float sfull = accS[m][n][jj];
        const float num   = accN[m][n][jj];
        const float nd    = accD[m][n][jj];
        const float rnij  = rsqrtf(fmaxf(nd, 1e-24f));
        const float sim   = num * rni * rnij;
        const float d     = fabsf(sfull - sim);
        if (gi != gj) sum += d;
      }
    }
  }
  for (int off = 32; off > 0; off >>= 1) sum += __shfl_down(sum, off);
  if (lane == 0) red[wv] = sum;
  __syncthreads();
  if (t == 0) {
    float bs = 0.f;
    for (int w = 0; w < 8; ++w) bs += red[w];
    const float scale = 1.0f / (8192.0f * 8191.0f);
    atomicAdd(out, bs * scale);
  }
}

extern "C" void kernel_launch(void* const* d_in, const int* in_sizes, int n_in,
                              void* d_out, int out_size, void* d_ws, size_t ws_size,
                              hipStream_t stream) {
  const float* f    = (const float*)d_in[0];   // full_emb [8192,768] fp32
  const float* mask = (const float*)d_in[1];   // query_mask [8192,768] fp32
  float* out = (float*)d_out;                  // scalar loss

  const size_t need = 4 * PANEL_BYTES + (size_t)B_ROWS * sizeof(float);
  if (ws_size >= need) {
    unsigned short* pF   = (unsigned short*)d_ws;
    unsigned short* pFM2 = pF + PANEL_ELEMS;
    unsigned short* pM2  = pFM2 + PANEL_ELEMS;
    unsigned short* pF2  = pM2 + PANEL_ELEMS;
    float* rn = (float*)(pF2 + PANEL_ELEMS);
    hipMemsetAsync(rn, 0, B_ROWS * sizeof(float), stream);
    hipMemsetAsync(out, 0, sizeof(float), stream);
    convert_kernel<<<(B_ROWS * (D_DIM / 8)) / 256, 256, 0, stream>>>(
        f, mask, pF, pFM2, pM2, pF2, rn);
    dim3 grid(B_ROWS / BJ, B_ROWS / BI);   // 32 x 64
    fused_loss_bf16_kernel<<<grid, NTHREADS, 0, stream>>>(pF, pFM2, pM2, pF2, rn, out);
  } else {
    float* rn_i = (float*)d_ws;
    rownorm_zero_kernel<<<B_ROWS / 4, 256, 0, stream>>>(f, mask, rn_i, out);
    dim3 grid(B_ROWS / 128, B_ROWS / 128);
    fused_loss_kernel<<<grid, NTHREADS, 0, stream>>>(f, mask, rn_i, out);
  }
}

// Round 6
// 284.513 us; speedup vs baseline: 1.2853x; 1.2791x over previous
//
#include <hip/hip_runtime.h>
#include <hip/hip_bf16.h>

// Problem constants (fixed by reference setup_inputs)
#define B_ROWS 8192
#define D_DIM  768

// Main-kernel tile config: 128(I) x 256(J) block tile, K-step 64 (fp8),
// 512 threads = 8 waves (2 wm x 4 wn), each wave owns a 64x64 output tile
// = 4x4 fragments of 16x16 per GEMM; 2 fp8 MFMAs per fragment per K-step.
#define BI 128
#define BJ 256
#define BK 64
#define NTHREADS 512
#define KTILES (D_DIM / BK)            // 12
#define TILE_BYTES (128 * BK)          // 8192 B per fp8 panel-tile (128 rows x 64)
#define PANEL_BYTES ((size_t)B_ROWS * (size_t)D_DIM)   // 6291456 B (fp8)

// LDS byte offsets: F(8192) FM2(8192) M2(8192) BF(16384) BF2(16384)
#define LDS_F    0
#define LDS_FM2  8192
#define LDS_M2   16384
#define LDS_BF   24576
#define LDS_BF2  40960
#define LDSBUF_BYTES 57344             // x2 = 114688 B

typedef __attribute__((ext_vector_type(8))) short bf16x8;           // bf16 frag (fallback)
typedef __attribute__((ext_vector_type(8))) unsigned short u16x8;   // 16B vector store
typedef __attribute__((ext_vector_type(4))) float f32x4;            // 16x16 C/D frag
typedef __attribute__((ext_vector_type(2))) long l64x2;             // two fp8 frags (16B)

__device__ __forceinline__ unsigned short f2bf(float x) {
  unsigned int u = __float_as_uint(x);
  u += 0x7fffu + ((u >> 16) & 1u);
  return (unsigned short)(u >> 16);
}

// fp32 -> OCP e4m3fn, round-to-nearest-even, saturate to 448. Branch-light,
// no header dependency. Valid for all finite inputs.
__device__ __forceinline__ unsigned int f2fp8(float x) {
  unsigned int u = __float_as_uint(x);
  unsigned int s = (u >> 24) & 0x80u;
  unsigned int au = u & 0x7FFFFFFFu;
  if (au < 0x3C800000u) {                  // |x| < 2^-6: fp8-subnormal region
    int k = (int)rintf(__uint_as_float(au) * 512.0f);   // multiples of 2^-9
    return s | (unsigned int)k;            // k==8 rolls into smallest normal
  }
  unsigned int m = au & 0x7FFFFFu;
  unsigned int e = au >> 23;               // >= 121
  unsigned int keep = m >> 20;
  unsigned int rest = m & 0xFFFFFu;
  keep += (rest > 0x80000u) || (rest == 0x80000u && (keep & 1u));
  unsigned int v = ((e - 120u) << 3) + keep;   // carry from keep ok
  if (v > 0x7Eu) v = 0x7Eu;                // clamp to 448
  return s | v;
}

__device__ __forceinline__ float4 f4mul(float4 a, float4 b) {
  return make_float4(a.x * b.x, a.y * b.y, a.z * b.z, a.w * b.w);
}

__device__ __forceinline__ u16x8 cvt8(float4 a, float4 b) {
  u16x8 v;
  v[0] = f2bf(a.x); v[1] = f2bf(a.y); v[2] = f2bf(a.z); v[3] = f2bf(a.w);
  v[4] = f2bf(b.x); v[5] = f2bf(b.y); v[6] = f2bf(b.z); v[7] = f2bf(b.w);
  return v;
}

// pack 8 floats -> 8 e4m3 bytes in one 8B store value
__device__ __forceinline__ unsigned long long pack8(float4 a, float4 b) {
  unsigned long long u = 0;
  u |= (unsigned long long)f2fp8(a.x);
  u |= (unsigned long long)f2fp8(a.y) << 8;
  u |= (unsigned long long)f2fp8(a.z) << 16;
  u |= (unsigned long long)f2fp8(a.w) << 24;
  u |= (unsigned long long)f2fp8(b.x) << 32;
  u |= (unsigned long long)f2fp8(b.y) << 40;
  u |= (unsigned long long)f2fp8(b.z) << 48;
  u |= (unsigned long long)f2fp8(b.w) << 56;
  return u;
}

// Direct global->LDS async copy, 16B per lane (wave-uniform LDS base + lane*16).
__device__ __forceinline__ void gload16(const void* g, void* l) {
  __builtin_amdgcn_global_load_lds(
      (const __attribute__((address_space(1))) unsigned int*)(uintptr_t)g,
      (__attribute__((address_space(3))) unsigned int*)(unsigned int)(uintptr_t)l,
      16, 0, 0);
}

// Pre-pass: fp32 inputs -> four e4m3 panels, tiled panel[tr][tk][128][64B].
// Within a row's 64B K-tile: byte p = c*16 + h*8 + b holds logical k = h*32+c*8+b
// (so one 16B chunk c = the two 8B half-k frags lane ch==c needs), and chunks are
// XOR-swizzled c' = c ^ ((row>>1)&3) for conflict-free ds_read_b128 (R2-proven;
// k-permutation is harmless: applied identically to A and B panels).
// FUSED: rn[r] += sum_d f^2 m^2 (fp32 exact; rn pre-zeroed).
__global__ __launch_bounds__(256) void convert_kernel(
    const float* __restrict__ f, const float* __restrict__ mask,
    unsigned char* __restrict__ pF, unsigned char* __restrict__ pFM2,
    unsigned char* __restrict__ pM2, unsigned char* __restrict__ pF2,
    float* __restrict__ rn) {
  const int g = blockIdx.x * 256 + threadIdx.x;   // 8192*96 chunks of 8 elems
  const int r = g / (D_DIM / 8);
  const int chunk = g - r * (D_DIM / 8);          // 0..95
  const float* fr = f + (size_t)r * D_DIM + chunk * 8;
  const float* mr = mask + (size_t)r * D_DIM + chunk * 8;
  float4 fv0 = *(const float4*)(fr);
  float4 fv1 = *(const float4*)(fr + 4);
  float4 mv0 = *(const float4*)(mr);
  float4 mv1 = *(const float4*)(mr + 4);
  float4 m20 = f4mul(mv0, mv0), m21 = f4mul(mv1, mv1);
  float4 fm0 = f4mul(fv0, m20), fm1 = f4mul(fv1, m21);
  float4 f20 = f4mul(fv0, fv0), f21 = f4mul(fv1, fv1);

  const int tr = r >> 7, rr = r & 127;
  const int tk = chunk >> 3;                      // K-64 tile 0..11
  const int c8 = chunk & 7;                       // 8B group within tile
  const int h  = c8 >> 2;                         // k-half
  const int c  = c8 & 3;                          // 16B chunk
  const int cs = c ^ ((rr >> 1) & 3);             // swizzled chunk
  const size_t off = ((size_t)((tr * KTILES + tk) * 128 + rr)) * 64 + cs * 16 + h * 8;
  *(unsigned long long*)(pF + off)   = pack8(fv0, fv1);
  *(unsigned long long*)(pFM2 + off) = pack8(fm0, fm1);
  *(unsigned long long*)(pM2 + off)  = pack8(m20, m21);
  *(unsigned long long*)(pF2 + off)  = pack8(f20, f21);

  float s = f20.x * m20.x + f20.y * m20.y + f20.z * m20.z + f20.w * m20.w
          + f21.x * m21.x + f21.y * m21.y + f21.z * m21.z + f21.w * m21.w;
  for (int o = 16; o > 0; o >>= 1) s += __shfl_down(s, o, 32);
  if ((threadIdx.x & 31) == 0) atomicAdd(&rn[r], s);
}

// Main kernel: fused triple-GEMM + loss, fp8 e4m3, 16x16x32 MFMA, BK=64
// (one ds_read_b128 feeds TWO MFMAs per fragment). R3-proven 2-barrier loop:
// prefetch issued before compute, single vmcnt(0)+barrier after.
//  accS = f_i . f_j ; accN = (f_i*m2_i) . f_j ; accD = m2_i . f_j^2
__global__ __launch_bounds__(NTHREADS) void fused_loss_fp8_kernel(
    const unsigned char* __restrict__ pF, const unsigned char* __restrict__ pFM2,
    const unsigned char* __restrict__ pM2, const unsigned char* __restrict__ pF2,
    const float* __restrict__ rn, float* __restrict__ out) {
  __shared__ unsigned char lds[2 * LDSBUF_BYTES];
  __shared__ float red[8];

  const int t    = threadIdx.x;
  const int lane = t & 63;
  const int wv   = t >> 6;        // wave id 0..7
  const int wm   = wv >> 2;       // 0..1  (row group of 64)
  const int wn   = wv & 3;        // 0..3  (col group of 64)
  const int frg  = lane & 15;     // fragment row
  const int ch   = lane >> 4;     // fragment k-chunk (16B = both k-halves)

  const int trA = blockIdx.y;     // i0 = trA*128
  const int trB = blockIdx.x;     // j0 = trB*256 -> panel row-tiles 2trB, 2trB+1
  const int te  = t * 16;         // staging byte offset (16B per thread)

  const size_t baseA  = (size_t)(trA * KTILES) * TILE_BYTES;
  const size_t baseB0 = (size_t)((2 * trB) * KTILES) * TILE_BYTES;
  const size_t baseB1 = (size_t)((2 * trB + 1) * KTILES) * TILE_BYTES;

  // Precomputed swizzled ds_read byte offsets (fixed per thread).
  int offA[4], offB[4];
#pragma unroll
  for (int m = 0; m < 4; ++m) {
    const int rr = wm * 64 + m * 16 + frg;            // 0..127
    offA[m] = rr * 64 + ((ch ^ ((rr >> 1) & 3)) << 4);
  }
#pragma unroll
  for (int n = 0; n < 4; ++n) {
    const int rB = wn * 64 + n * 16 + frg;            // 0..255
    const int rt = rB >> 7, rr = rB & 127;
    offB[n] = rt * TILE_BYTES + rr * 64 + ((ch ^ ((rr >> 1) & 3)) << 4);
  }

  f32x4 accS[4][4], accN[4][4], accD[4][4];
#pragma unroll
  for (int m = 0; m < 4; ++m)
#pragma unroll
    for (int n = 0; n < 4; ++n) {
      accS[m][n] = {0.f, 0.f, 0.f, 0.f};
      accN[m][n] = {0.f, 0.f, 0.f, 0.f};
      accD[m][n] = {0.f, 0.f, 0.f, 0.f};
    }

#define STAGE(b, tk)                                                          \
  do {                                                                        \
    const size_t _tA  = baseA  + (size_t)(tk) * TILE_BYTES + te;              \
    const size_t _tB0 = baseB0 + (size_t)(tk) * TILE_BYTES + te;              \
    const size_t _tB1 = baseB1 + (size_t)(tk) * TILE_BYTES + te;              \
    gload16(pF   + _tA,  (b) + LDS_F   + te);                                 \
    gload16(pFM2 + _tA,  (b) + LDS_FM2 + te);                                 \
    gload16(pM2  + _tA,  (b) + LDS_M2  + te);                                 \
    gload16(pF   + _tB0, (b) + LDS_BF  + te);                                 \
    gload16(pF   + _tB1, (b) + LDS_BF  + TILE_BYTES + te);                    \
    gload16(pF2  + _tB0, (b) + LDS_BF2 + te);                                 \
    gload16(pF2  + _tB1, (b) + LDS_BF2 + TILE_BYTES + te);                    \
  } while (0)

  unsigned char* const buf0 = lds;
  unsigned char* const buf1 = lds + LDSBUF_BYTES;

  STAGE(buf0, 0);
  asm volatile("s_waitcnt vmcnt(0)" ::: "memory");
  __syncthreads();

  int cur = 0;
  for (int tk = 0; tk < KTILES; ++tk) {
    unsigned char* const cb = cur ? buf1 : buf0;
    unsigned char* const nb = cur ? buf0 : buf1;
    if (tk + 1 < KTILES) STAGE(nb, tk + 1);   // prefetch issued BEFORE compute

    l64x2 bF[4], bF2[4];
#pragma unroll
    for (int n = 0; n < 4; ++n) {
      bF[n]  = *(const l64x2*)(cb + LDS_BF  + offB[n]);
      bF2[n] = *(const l64x2*)(cb + LDS_BF2 + offB[n]);
    }
#pragma unroll
    for (int m = 0; m < 4; ++m) {
      l64x2 aF = *(const l64x2*)(cb + LDS_F   + offA[m]);
      l64x2 aN = *(const l64x2*)(cb + LDS_FM2 + offA[m]);
      l64x2 aD = *(const l64x2*)(cb + LDS_M2  + offA[m]);
#pragma unroll
      for (int n = 0; n < 4; ++n) {
        accS[m][n] = __builtin_amdgcn_mfma_f32_16x16x32_fp8_fp8(aF.x, bF[n].x,  accS[m][n], 0, 0, 0);
        accN[m][n] = __builtin_amdgcn_mfma_f32_16x16x32_fp8_fp8(aN.x, bF[n].x,  accN[m][n], 0, 0, 0);
        accD[m][n] = __builtin_amdgcn_mfma_f32_16x16x32_fp8_fp8(aD.x, bF2[n].x, accD[m][n], 0, 0, 0);
        accS[m][n] = __builtin_amdgcn_mfma_f32_16x16x32_fp8_fp8(aF.y, bF[n].y,  accS[m][n], 0, 0, 0);
        accN[m][n] = __builtin_amdgcn_mfma_f32_16x16x32_fp8_fp8(aN.y, bF[n].y,  accN[m][n], 0, 0, 0);
        accD[m][n] = __builtin_amdgcn_mfma_f32_16x16x32_fp8_fp8(aD.y, bF2[n].y, accD[m][n], 0, 0, 0);
      }
    }
    asm volatile("s_waitcnt vmcnt(0)" ::: "memory");
    __syncthreads();
    cur ^= 1;
  }
#undef STAGE

  // ---- epilogue: pointwise loss + off-diagonal masked reduction ----
  // 16x16 C/D layout (m89-verified, dtype-independent): col = lane&15,
  // row = (lane>>4)*4 + reg
  float sum = 0.f;
  const int r4 = (lane >> 4) * 4;
  const int cc = lane & 15;
  const int i0 = trA * BI;
  const int j0 = trB * BJ;
#pragma unroll
  for (int m = 0; m < 4; ++m) {
    const int gi_base = i0 + wm * 64 + m * 16 + r4;
#pragma unroll
    for (int jj = 0; jj < 4; ++jj) {
      const int gi = gi_base + jj;
      // rn holds sum_d f^2 m^2 ; 1/max(sqrt(s),1e-12) == rsqrt(max(s,1e-24))
      const float rni = rsqrtf(fmaxf(rn[gi], 1e-24f));
#pragma unroll
      for (int n = 0; n < 4; ++n) {
        const int gj = j0 + wn * 64 + n * 16 + cc;
        const float sfull = accS[m][n][jj];
        const float num   = accN[m][n][jj];
        const float nd    = accD[m][n][jj];
        const float rnij  = rsqrtf(fmaxf(nd, 1e-24f));
        const float sim   = num * rni * rnij;
        const float d     = fabsf(sfull - sim);
        if (gi != gj) sum += d;
      }
    }
  }
  for (int off = 32; off > 0; off >>= 1) sum += __shfl_down(sum, off);
  if (lane == 0) red[wv] = sum;
  __syncthreads();
  if (t == 0) {
    float bs = 0.f;
    for (int w = 0; w < 8; ++w) bs += red[w];
    const float scale = 1.0f / (8192.0f * 8191.0f);
    atomicAdd(out, bs * scale);
  }
}

// ---------------- Fallback path (ws too small): round-1 kernels ---------------
__global__ __launch_bounds__(256) void rownorm_zero_kernel(
    const float* __restrict__ f, const float* __restrict__ mask,
    float* __restrict__ rn_i, float* __restrict__ out) {
  if (blockIdx.x == 0 && threadIdx.x == 0) out[0] = 0.0f;
  const int wv = threadIdx.x >> 6;
  const int lane = threadIdx.x & 63;
  const int row = blockIdx.x * 4 + wv;
  const float* fr = f + (size_t)row * D_DIM;
  const float* mr = mask + (size_t)row * D_DIM;
  float s = 0.f;
  for (int d = lane; d < D_DIM; d += 64) {
    float v = fr[d] * mr[d];
    s += v * v;
  }
  for (int off = 32; off > 0; off >>= 1) s += __shfl_down(s, off);
  if (lane == 0) rn_i[row] = 1.0f / fmaxf(sqrtf(s), 1e-12f);
}

__global__ __launch_bounds__(NTHREADS, 2) void fused_loss_kernel(
    const float* __restrict__ f, const float* __restrict__ mask,
    const float* __restrict__ rn_i, float* __restrict__ out) {
  __shared__ unsigned short sF[128][32];
  __shared__ unsigned short sFM2[128][32];
  __shared__ unsigned short sM2[128][32];
  __shared__ unsigned short sBF[128][32];
  __shared__ unsigned short sBF2[128][32];
  __shared__ float red[8];

  const int t    = threadIdx.x;
  const int lane = t & 63;
  const int wv   = t >> 6;
  const int wm   = wv >> 2;
  const int wn   = wv & 3;
  const int frg  = lane & 15;
  const int ko   = (lane >> 4) * 8;

  const int i0 = blockIdx.y * 128;
  const int j0 = blockIdx.x * 128;
  const int ar = t >> 2;
  const int ac = (t & 3) * 8;

  f32x4 accS[4][2], accN[4][2], accD[4][2];
  for (int m = 0; m < 4; ++m)
    for (int n = 0; n < 2; ++n) {
      accS[m][n] = {0.f, 0.f, 0.f, 0.f};
      accN[m][n] = {0.f, 0.f, 0.f, 0.f};
      accD[m][n] = {0.f, 0.f, 0.f, 0.f};
    }

  const float* fA = f    + (size_t)(i0 + ar) * D_DIM + ac;
  const float* mA = mask + (size_t)(i0 + ar) * D_DIM + ac;
  const float* fB = f    + (size_t)(j0 + ar) * D_DIM + ac;

  for (int k0 = 0; k0 < D_DIM; k0 += 32) {
    __syncthreads();
    float4 fa0 = *(const float4*)(fA + k0);
    float4 fa1 = *(const float4*)(fA + k0 + 4);
    float4 ma0 = *(const float4*)(mA + k0);
    float4 ma1 = *(const float4*)(mA + k0 + 4);
    float4 fb0 = *(const float4*)(fB + k0);
    float4 fb1 = *(const float4*)(fB + k0 + 4);
    float4 m20 = f4mul(ma0, ma0), m21 = f4mul(ma1, ma1);
    float4 fm0 = f4mul(fa0, m20), fm1 = f4mul(fa1, m21);
    float4 f20 = f4mul(fb0, fb0), f21 = f4mul(fb1, fb1);
    *(u16x8*)&sF[ar][ac]   = cvt8(fa0, fa1);
    *(u16x8*)&sFM2[ar][ac] = cvt8(fm0, fm1);
    *(u16x8*)&sM2[ar][ac]  = cvt8(m20, m21);
    *(u16x8*)&sBF[ar][ac]  = cvt8(fb0, fb1);
    *(u16x8*)&sBF2[ar][ac] = cvt8(f20, f21);
    __syncthreads();
    bf16x8 bF[2], bF2[2];
    for (int n = 0; n < 2; ++n) {
      bF[n]  = *(const bf16x8*)&sBF [wn * 32 + n * 16 + frg][ko];
      bF2[n] = *(const bf16x8*)&sBF2[wn * 32 + n * 16 + frg][ko];
    }
#pragma unroll
    for (int m = 0; m < 4; ++m) {
      bf16x8 aF = *(const bf16x8*)&sF  [wm * 64 + m * 16 + frg][ko];
      bf16x8 aN = *(const bf16x8*)&sFM2[wm * 64 + m * 16 + frg][ko];
      bf16x8 aD = *(const bf16x8*)&sM2 [wm * 64 + m * 16 + frg][ko];
#pragma unroll
      for (int n = 0; n < 2; ++n) {
        accS[m][n] = __builtin_amdgcn_mfma_f32_16x16x32_bf16(aF, bF[n],  accS[m][n], 0, 0, 0);
        accN[m][n] = __builtin_amdgcn_mfma_f32_16x16x32_bf16(aN, bF[n],  accN[m][n], 0, 0, 0);
        accD[m][n] = __builtin_amdgcn_mfma_f32_16x16x32_bf16(aD, bF2[n], accD[m][n], 0, 0, 0);
      }
    }
  }

  float sum = 0.f;
  const int r4 = (lane >> 4) * 4;
  const int cc = lane & 15;
#pragma unroll
  for (int m = 0; m < 4; ++m) {
    const int gi_base = i0 + wm * 64 + m * 16 + r4;
#pragma unroll
    for (int jj = 0; jj < 4; ++jj) {
      const int gi = gi_base + jj;
      const float rni = rn_i[gi];
#pragma unroll
      for (int n = 0; n < 2; ++n) {
        const int gj = j0 + wn * 32 + n * 16 + cc;
        const float sfull = accS[m][n][jj];
        const float num   = accN[m][n][jj];
        const float nd    = accD[m][n][jj];
        const float rnij  = rsqrtf(fmaxf(nd, 1e-24f));
        const float sim   = num * rni * rnij;
        const float d     = fabsf(sfull - sim);
        if (gi != gj) sum += d;
      }
    }
  }
  for (int off = 32; off > 0; off >>= 1) sum += __shfl_down(sum, off);
  if (lane == 0) red[wv] = sum;
  __syncthreads();
  if (t == 0) {
    float bs = 0.f;
    for (int w = 0; w < 8; ++w) bs += red[w];
    const float scale = 1.0f / (8192.0f * 8191.0f);
    atomicAdd(out, bs * scale);
  }
}

extern "C" void kernel_launch(void* const* d_in, const int* in_sizes, int n_in,
                              void* d_out, int out_size, void* d_ws, size_t ws_size,
                              hipStream_t stream) {
  const float* f    = (const float*)d_in[0];   // full_emb [8192,768] fp32
  const float* mask = (const float*)d_in[1];   // query_mask [8192,768] fp32
  float* out = (float*)d_out;                  // scalar loss

  const size_t need = 4 * PANEL_BYTES + (size_t)B_ROWS * sizeof(float);
  if (ws_size >= need) {
    unsigned char* pF   = (unsigned char*)d_ws;
    unsigned char* pFM2 = pF + PANEL_BYTES;
    unsigned char* pM2  = pFM2 + PANEL_BYTES;
    unsigned char* pF2  = pM2 + PANEL_BYTES;
    float* rn = (float*)(pF2 + PANEL_BYTES);
    hipMemsetAsync(rn, 0, B_ROWS * sizeof(float), stream);
    hipMemsetAsync(out, 0, sizeof(float), stream);
    convert_kernel<<<(B_ROWS * (D_DIM / 8)) / 256, 256, 0, stream>>>(
        f, mask, pF, pFM2, pM2, pF2, rn);
    dim3 grid(B_ROWS / BJ, B_ROWS / BI);   // 32 x 64
    fused_loss_fp8_kernel<<<grid, NTHREADS, 0, stream>>>(pF, pFM2, pM2, pF2, rn, out);
  } else {
    float* rn_i = (float*)d_ws;
    rownorm_zero_kernel<<<B_ROWS / 4, 256, 0, stream>>>(f, mask, rn_i, out);
    dim3 grid(B_ROWS / 128, B_ROWS / 128);
    fused_loss_kernel<<<grid, NTHREADS, 0, stream>>>(f, mask, rn_i, out);
  }
}